// Round 17
// baseline (541.377 us; speedup 1.0000x reference)
//
#include <hip/hip_runtime.h>
#include <math.h>

#define TOK 25

typedef __attribute__((ext_vector_type(8))) short short8_t;   // 8 bf16 (MFMA frag)
typedef __attribute__((ext_vector_type(4))) float f32x4_t;    // MFMA acc
typedef __attribute__((ext_vector_type(8))) float floatx8;
typedef __attribute__((ext_vector_type(4))) float floatx4;
typedef __attribute__((ext_vector_type(8))) __bf16 bf16x8_t;
typedef __attribute__((ext_vector_type(4))) __bf16 bf16x4_t;

// f32x8 -> bf16x8 via v_cvt_pk_bf16_f32 (compiler-lowered), as MFMA short8 frag
__device__ __forceinline__ short8_t cvt8(floatx8 f) {
  return __builtin_bit_cast(short8_t, __builtin_convertvector(f, bf16x8_t));
}
__device__ __forceinline__ uint2 cvt4pack(float4 v) {
  floatx4 f = {v.x, v.y, v.z, v.w};
  return __builtin_bit_cast(uint2, __builtin_convertvector(f, bf16x4_t));
}
__device__ __forceinline__ unsigned long long pack4ull(f32x4_t v) {
  floatx4 f = {v[0], v[1], v[2], v[3]};
  return __builtin_bit_cast(unsigned long long,
                            __builtin_convertvector(f, bf16x4_t));
}
__device__ __forceinline__ unsigned short bf1(float f) {
  return __builtin_bit_cast(unsigned short, (__bf16)f);
}

// Partial layout: uint2 part[s][N/16][2(half)][64(lane)]
//   lane = lg*16+lm ; uint2 = 4 bf16 rows {half*16+lg*4+0..3} of col ct*16+lm.
// Partials stored/loaded with AGENT-scope atomics (write-through): per-XCD L2s
// are not cross-coherent, so cross-block consumption needs a coherent point.

__device__ __forceinline__ void store_part(uint2* p, unsigned long long v) {
  __hip_atomic_store((unsigned long long*)p, v, __ATOMIC_RELAXED,
                     __HIP_MEMORY_SCOPE_AGENT);
}
__device__ __forceinline__ uint2 load_part(const uint2* p) {
  unsigned long long raw = __hip_atomic_load(
      (const unsigned long long*)p, __ATOMIC_RELAXED, __HIP_MEMORY_SCOPE_AGENT);
  return __builtin_bit_cast(uint2, raw);
}

// ---------------- last-arriver finalize: sum S slices + bias (+gelu)(+res)
template <int G, int S, int GELU, int RES, int OBF>
__device__ __forceinline__ void k_finalize(const uint2* __restrict__ part,
                                           const float* __restrict__ bias,
                                           const float* __restrict__ res,
                                           void* __restrict__ outv, int bx,
                                           int N, int tid) {
  const long base = (long)bx * (G * 4) * 128;  // block covers 4G col-tiles
  const long stride = (long)N * 8;             // uint2 per s-slice
#pragma unroll
  for (int it = 0; it < 2 * G; ++it) {
    long p = base + (long)it * 256 + tid;
    int lane = (int)(p & 63);
    int half = (int)((p >> 6) & 1);
    long ct = p >> 7;
    int lm = lane & 15, lg = lane >> 4;
    int col = (int)(ct * 16 + lm);
    const uint2* pp = part + p;
    float a[4] = {0.f, 0.f, 0.f, 0.f};
#pragma unroll 8
    for (int s = 0; s < S; ++s) {
      uint2 u = load_part(&pp[(long)s * stride]);
      a[0] += __builtin_bit_cast(float, (u.x & 0xffffu) << 16);
      a[1] += __builtin_bit_cast(float, u.x & 0xffff0000u);
      a[2] += __builtin_bit_cast(float, (u.y & 0xffffu) << 16);
      a[3] += __builtin_bit_cast(float, u.y & 0xffff0000u);
    }
    const float bb = bias[col];
#pragma unroll
    for (int r = 0; r < 4; ++r) {
      a[r] += bb;
      if (GELU) a[r] = 0.5f * a[r] * (1.f + erff(a[r] * 0.70710678118654752f));
    }
    const int row0 = half * 16 + lg * 4;
#pragma unroll
    for (int r = 0; r < 4; ++r) {
      int row = row0 + r;
      if (row < TOK) {
        float v = a[r];
        if (RES) v += res[(long)row * N + col];
        if (OBF) {
          ((unsigned short*)outv)[(long)row * N + col] = bf1(v);
        } else {
          ((float*)outv)[(long)row * N + col] = v;
        }
      }
    }
  }
}

// ---------------- MFMA GEMM: A_bf[25][K] * W -> partials; last block finalizes.
// Block: 4 waves, 64*G cols; wave owns 16*G cols. A staged in LDS as bf16.
// D-step-ahead register prefetch ((D+1)-buffer rotation, full unroll).
// WT=0: W[K][N].  WT=1: W[N][K].
template <int KC, int WT, int G, int D, int S, int GELU, int RES, int OBF>
__global__ __launch_bounds__(256) void k_mfma(
    const unsigned short* __restrict__ A, const float* __restrict__ W,
    uint2* __restrict__ part, const float* __restrict__ bias,
    const float* __restrict__ res, void* __restrict__ outv,
    int* __restrict__ cnt, int K, int N) {
  constexpr int LDA = KC + 8;  // bf16 elems/row; +16B pad
  constexpr int NS = KC / 32;
  __shared__ __align__(16) unsigned short As[TOK * LDA];
  __shared__ int doit;
  const int tid = threadIdx.x;
  const int lane = tid & 63;
  const int lm = lane & 15;
  const int lg = lane >> 4;
  const int wv = tid >> 6;
  const int s = blockIdx.y;
  const int k0 = s * KC;
  const int c0 = blockIdx.x * (64 * G) + wv * (16 * G);
  for (int i = tid; i < TOK * (KC / 8); i += 256) {
    int r = i / (KC / 8);
    int o = i - r * (KC / 8);
    uint4 v = *reinterpret_cast<const uint4*>(A + (long)r * K + k0 + o * 8);
    *reinterpret_cast<uint4*>(&As[r * LDA + o * 8]) = v;
  }
  __syncthreads();
  const int r1 = 16 + lm;
  const int r1c = (r1 < TOK) ? r1 : 0;
  f32x4_t acc[G][2];
#pragma unroll
  for (int g = 0; g < G; ++g) {
    acc[g][0] = (f32x4_t){0.f, 0.f, 0.f, 0.f};
    acc[g][1] = (f32x4_t){0.f, 0.f, 0.f, 0.f};
  }
  auto loadW = [&](int ks, floatx8(&dst)[G]) {
    const int kb = k0 + ks + lg * 8;
    if (WT == 0) {
      const float* bp = W + (long)kb * N + c0 + lm;
#pragma unroll
      for (int j = 0; j < 8; ++j) {
        const float* bj = bp + (long)j * N;
#pragma unroll
        for (int g = 0; g < G; ++g) dst[g][j] = bj[g * 16];
      }
    } else {
#pragma unroll
      for (int g = 0; g < G; ++g) {
        const float* bp = W + (long)(c0 + g * 16 + lm) * K + kb;
        float4 b0 = *reinterpret_cast<const float4*>(bp);
        float4 b1 = *reinterpret_cast<const float4*>(bp + 4);
        dst[g] = (floatx8){b0.x, b0.y, b0.z, b0.w, b1.x, b1.y, b1.z, b1.w};
      }
    }
  };
  floatx8 wb[D + 1][G];
  loadW(0, wb[0]);
  if (D >= 2 && NS > 1) loadW(32, wb[1 % (D + 1)]);
#pragma unroll
  for (int st = 0; st < NS; ++st) {
    if (st + D < NS) loadW((st + D) * 32, wb[(st + D) % (D + 1)]);
    short8_t av0 =
        *reinterpret_cast<const short8_t*>(&As[lm * LDA + st * 32 + lg * 8]);
    short8_t av1 =
        *reinterpret_cast<const short8_t*>(&As[r1c * LDA + st * 32 + lg * 8]);
#pragma unroll
    for (int g = 0; g < G; ++g) {
      short8_t bv = cvt8(wb[st % (D + 1)][g]);
      acc[g][0] = __builtin_amdgcn_mfma_f32_16x16x32_bf16(av0, bv, acc[g][0], 0, 0, 0);
      acc[g][1] = __builtin_amdgcn_mfma_f32_16x16x32_bf16(av1, bv, acc[g][1], 0, 0, 0);
    }
  }
  // ---- packed partial store (agent-scope, write-through)
  const long sbase = (long)s * N * 8;
#pragma unroll
  for (int g = 0; g < G; ++g) {
    long t = ((long)(c0 >> 4) + g) * 128;
    store_part(&part[sbase + t + lane], pack4ull(acc[g][0]));
    store_part(&part[sbase + t + 64 + lane], pack4ull(acc[g][1]));
  }
  // ---- last arriver for this column strip finalizes
  if (tid == 0) {
    int old = __hip_atomic_fetch_add(&cnt[blockIdx.x], 1, __ATOMIC_ACQ_REL,
                                     __HIP_MEMORY_SCOPE_AGENT);
    doit = (old == S - 1);
  }
  __syncthreads();
  if (doit) k_finalize<G, S, GELU, RES, OBF>(part, bias, res, outv,
                                             blockIdx.x, N, tid);
}

// ---------------- patch-embed MFMA GEMM: A gathered from x. W=pe_w[N][K].
template <int KC, int G, int D, int S>
__global__ __launch_bounds__(256) void k_mfma_pe(
    const float* __restrict__ x, const float* __restrict__ W,
    uint2* __restrict__ part, const float* __restrict__ bias,
    const float* __restrict__ res, float* __restrict__ outv,
    int* __restrict__ cnt, int K, int N) {
  constexpr int LDA = KC + 8;
  constexpr int NS = KC / 32;
  __shared__ __align__(16) unsigned short As[TOK * LDA];
  __shared__ int doit;
  const int tid = threadIdx.x;
  const int lane = tid & 63;
  const int lm = lane & 15;
  const int lg = lane >> 4;
  const int wv = tid >> 6;
  const int s = blockIdx.y;
  const int k0 = s * KC;
  const int c0 = blockIdx.x * (64 * G) + wv * (16 * G);
  for (int i = tid; i < TOK * (KC / 8); i += 256) {
    int r = i / (KC / 8);
    int o = i - r * (KC / 8);
    int kb = k0 + o * 8;
    int c = kb >> 4;
    int kh0 = (kb >> 2) & 3;
    int py = r / 5, px = r - py * 5;
    const float* xp = x + c * 400 + (py * 4 + kh0) * 20 + px * 4;
    float4 lo = *reinterpret_cast<const float4*>(xp);
    float4 hi = *reinterpret_cast<const float4*>(xp + 20);
    floatx8 f = {lo.x, lo.y, lo.z, lo.w, hi.x, hi.y, hi.z, hi.w};
    *reinterpret_cast<short8_t*>(&As[r * LDA + o * 8]) = cvt8(f);
  }
  __syncthreads();
  const int r1 = 16 + lm;
  const int r1c = (r1 < TOK) ? r1 : 0;
  f32x4_t acc[G][2];
#pragma unroll
  for (int g = 0; g < G; ++g) {
    acc[g][0] = (f32x4_t){0.f, 0.f, 0.f, 0.f};
    acc[g][1] = (f32x4_t){0.f, 0.f, 0.f, 0.f};
  }
  auto loadW = [&](int ks, floatx8(&dst)[G]) {
    const int kb = k0 + ks + lg * 8;
#pragma unroll
    for (int g = 0; g < G; ++g) {
      const float* bp = W + (long)(c0 + g * 16 + lm) * K + kb;
      float4 b0 = *reinterpret_cast<const float4*>(bp);
      float4 b1 = *reinterpret_cast<const float4*>(bp + 4);
      dst[g] = (floatx8){b0.x, b0.y, b0.z, b0.w, b1.x, b1.y, b1.z, b1.w};
    }
  };
  floatx8 wb[D + 1][G];
  loadW(0, wb[0]);
  if (D >= 2 && NS > 1) loadW(32, wb[1 % (D + 1)]);
#pragma unroll
  for (int st = 0; st < NS; ++st) {
    if (st + D < NS) loadW((st + D) * 32, wb[(st + D) % (D + 1)]);
    short8_t av0 =
        *reinterpret_cast<const short8_t*>(&As[lm * LDA + st * 32 + lg * 8]);
    short8_t av1 =
        *reinterpret_cast<const short8_t*>(&As[r1c * LDA + st * 32 + lg * 8]);
#pragma unroll
    for (int g = 0; g < G; ++g) {
      short8_t bv = cvt8(wb[st % (D + 1)][g]);
      acc[g][0] = __builtin_amdgcn_mfma_f32_16x16x32_bf16(av0, bv, acc[g][0], 0, 0, 0);
      acc[g][1] = __builtin_amdgcn_mfma_f32_16x16x32_bf16(av1, bv, acc[g][1], 0, 0, 0);
    }
  }
  const long sbase = (long)s * N * 8;
#pragma unroll
  for (int g = 0; g < G; ++g) {
    long t = ((long)(c0 >> 4) + g) * 128;
    store_part(&part[sbase + t + lane], pack4ull(acc[g][0]));
    store_part(&part[sbase + t + 64 + lane], pack4ull(acc[g][1]));
  }
  if (tid == 0) {
    int old = __hip_atomic_fetch_add(&cnt[blockIdx.x], 1, __ATOMIC_ACQ_REL,
                                     __HIP_MEMORY_SCOPE_AGENT);
    doit = (old == S - 1);
  }
  __syncthreads();
  if (doit) k_finalize<G, S, 0, 1, 0>(part, bias, res, outv, blockIdx.x, N, tid);
}

// ---------------- LayerNorm over 4096, one block per token -> bf16 out
__global__ __launch_bounds__(256) void k_ln(const float* __restrict__ t,
                                            const float* __restrict__ g,
                                            const float* __restrict__ b,
                                            unsigned short* __restrict__ h) {
  const int n = blockIdx.x;
  const float4* row = reinterpret_cast<const float4*>(t + n * 4096);
  float s = 0.f, s2 = 0.f;
  float4 vbuf[4];
#pragma unroll
  for (int it = 0; it < 4; ++it) {
    float4 v = row[threadIdx.x + it * 256];
    vbuf[it] = v;
    s += v.x + v.y + v.z + v.w;
    s2 += v.x * v.x + v.y * v.y + v.z * v.z + v.w * v.w;
  }
#pragma unroll
  for (int off = 32; off >= 1; off >>= 1) {
    s += __shfl_down(s, off);
    s2 += __shfl_down(s2, off);
  }
  __shared__ float red[8];
  if ((threadIdx.x & 63) == 0) {
    red[threadIdx.x >> 6] = s;
    red[4 + (threadIdx.x >> 6)] = s2;
  }
  __syncthreads();
  float st = red[0] + red[1] + red[2] + red[3];
  float s2t = red[4] + red[5] + red[6] + red[7];
  float mean = st * (1.f / 4096.f);
  float var = s2t * (1.f / 4096.f) - mean * mean;
  float rstd = rsqrtf(var + 1e-5f);
  const float4* g4 = reinterpret_cast<const float4*>(g);
  const float4* b4 = reinterpret_cast<const float4*>(b);
  uint2* h2 = reinterpret_cast<uint2*>(h) + (long)n * 1024;
#pragma unroll
  for (int it = 0; it < 4; ++it) {
    int i = threadIdx.x + it * 256;
    float4 v = vbuf[it];
    float4 gg = g4[i];
    float4 bb = b4[i];
    float4 o;
    o.x = (v.x - mean) * rstd * gg.x + bb.x;
    o.y = (v.y - mean) * rstd * gg.y + bb.y;
    o.z = (v.z - mean) * rstd * gg.z + bb.z;
    o.w = (v.w - mean) * rstd * gg.w + bb.w;
    h2[i] = cvt4pack(o);
  }
}

// ---------------- fused attention: QK^T + softmax/64 + PV -> O_bf[25][4096]
__global__ __launch_bounds__(256) void k_attn(const float* __restrict__ qkv,
                                              unsigned short* __restrict__ o) {
  const int head = blockIdx.x;
  __shared__ float q[TOK][260];
  __shared__ float kk[TOK][260];
  __shared__ float att[TOK][TOK];
  const int d = threadIdx.x;
#pragma unroll
  for (int n = 0; n < TOK; ++n) {
    const long base = (long)n * 12288 + (head * 256 + d) * 3;
    q[n][d] = qkv[base];
    kk[n][d] = qkv[base + 1];
  }
  __syncthreads();
  for (int p = threadIdx.x; p < TOK * TOK; p += 256) {
    int i = p / TOK, j = p - i * TOK;
    float acc = 0.f;
#pragma unroll
    for (int c = 0; c < 256; c += 4) {
      float4 a = *reinterpret_cast<const float4*>(&q[i][c]);
      float4 bb = *reinterpret_cast<const float4*>(&kk[j][c]);
      acc = fmaf(a.x, bb.x, acc);
      acc = fmaf(a.y, bb.y, acc);
      acc = fmaf(a.z, bb.z, acc);
      acc = fmaf(a.w, bb.w, acc);
    }
    att[i][j] = acc;
  }
  __syncthreads();
  if (threadIdx.x < TOK) {
    const int i = threadIdx.x;
    float m = -1e30f;
    for (int j = 0; j < TOK; ++j) m = fmaxf(m, att[i][j]);
    float ssum = 0.f;
    float ex[TOK];
#pragma unroll
    for (int j = 0; j < TOK; ++j) {
      ex[j] = expf(att[i][j] - m);
      ssum += ex[j];
    }
    float inv = 1.f / (ssum * 64.f);  // softmax then /sqrt(4096)
#pragma unroll
    for (int j = 0; j < TOK; ++j) att[i][j] = ex[j] * inv;
  }
  __syncthreads();
  float acc[TOK];
#pragma unroll
  for (int i = 0; i < TOK; ++i) acc[i] = 0.f;
#pragma unroll
  for (int j = 0; j < TOK; ++j) {
    float vv = qkv[(long)j * 12288 + (head * 256 + d) * 3 + 2];
#pragma unroll
    for (int i = 0; i < TOK; ++i) acc[i] = fmaf(att[i][j], vv, acc[i]);
  }
#pragma unroll
  for (int i = 0; i < TOK; ++i)
    o[(long)i * 4096 + head * 256 + d] = bf1(acc[i]);
}

extern "C" void kernel_launch(void* const* d_in, const int* in_sizes, int n_in,
                              void* d_out, int out_size, void* d_ws, size_t ws_size,
                              hipStream_t stream) {
  (void)in_sizes; (void)n_in; (void)out_size; (void)ws_size;
  const float* x      = (const float*)d_in[0];
  const float* pe_w   = (const float*)d_in[1];
  const float* pe_b   = (const float*)d_in[2];
  const float* pos    = (const float*)d_in[3];
  const float* ln_g   = (const float*)d_in[4];
  const float* ln_b   = (const float*)d_in[5];
  const float* qkv_w  = (const float*)d_in[6];
  const float* qkv_b  = (const float*)d_in[7];
  const float* proj_w = (const float*)d_in[8];
  const float* proj_b = (const float*)d_in[9];
  const float* ff1_w  = (const float*)d_in[10];
  const float* ff1_b  = (const float*)d_in[11];
  const float* ff2_w  = (const float*)d_in[12];
  const float* ff2_b  = (const float*)d_in[13];
  float* out = (float*)d_out;

  float* ws = (float*)d_ws;
  float* T    = ws + 102400;    // 102400 f32
  unsigned short* H_bf = (unsigned short*)(ws + 204800);      // 102400 bf16
  float* QKV  = ws + 307200;    // 307200 f32
  unsigned short* O_bf = (unsigned short*)(ws + 614400);      // 102400 bf16
  unsigned short* G_bf = (unsigned short*)(ws + 716800);      // 409600 bf16
  int* CNT = (int*)(ws + 1126400);       // 256 ints, disjoint per GEMM
  uint2* PART = (uint2*)(ws + 1136400);  // max 12.6 MB (qkv)

  hipMemsetAsync(CNT, 0, 256 * sizeof(int), stream);

  // 1. patch embedding: KC=128 S=32, G=2 D=2, grid(32,32); finalize -> T (+pos)
  k_mfma_pe<128, 2, 2, 32><<<dim3(32, 32), 256, 0, stream>>>(
      x, pe_w, PART, pe_b, pos, T, CNT + 0, 4096, 4096);
  k_ln<<<25, 256, 0, stream>>>(T, ln_g, ln_b, H_bf);

  // 2. attention: qkv KC=256 S=16, G=2 D=2, grid(96,16); finalize -> QKV
  k_mfma<256, 0, 2, 2, 16, 0, 0, 0><<<dim3(96, 16), 256, 0, stream>>>(
      H_bf, qkv_w, PART, qkv_b, nullptr, QKV, CNT + 32, 4096, 12288);
  k_attn<<<16, 256, 0, stream>>>(QKV, O_bf);
  // proj KC=128 S=32, G=2 D=2, grid(32,32); finalize -> T (+T residual)
  k_mfma<128, 0, 2, 2, 32, 0, 1, 0><<<dim3(32, 32), 256, 0, stream>>>(
      O_bf, proj_w, PART, proj_b, T, T, CNT + 128, 4096, 4096);
  k_ln<<<25, 256, 0, stream>>>(T, ln_g, ln_b, H_bf);

  // 3. FFN: ff1 KC=256 S=16, G=4 D=1, grid(64,16); finalize GELU -> G_bf
  k_mfma<256, 0, 4, 1, 16, 1, 0, 1><<<dim3(64, 16), 256, 0, stream>>>(
      H_bf, ff1_w, PART, ff1_b, nullptr, G_bf, CNT + 160, 4096, 16384);
  // ff2 KC=512 S=32, G=2 D=2, grid(32,32); finalize -> out (+T residual)
  k_mfma<512, 0, 2, 2, 32, 0, 1, 0><<<dim3(32, 32), 256, 0, stream>>>(
      G_bf, ff2_w, PART, ff2_b, T, out, CNT + 224, 16384, 4096);
}

// Round 18
// 229.626 us; speedup vs baseline: 2.3577x; 2.3577x over previous
//
#include <hip/hip_runtime.h>
#include <math.h>

#define TOK 25

typedef __attribute__((ext_vector_type(8))) short short8_t;   // 8 bf16 (MFMA frag)
typedef __attribute__((ext_vector_type(4))) float f32x4_t;    // MFMA acc
typedef __attribute__((ext_vector_type(8))) float floatx8;
typedef __attribute__((ext_vector_type(4))) float floatx4;
typedef __attribute__((ext_vector_type(8))) __bf16 bf16x8_t;
typedef __attribute__((ext_vector_type(4))) __bf16 bf16x4_t;

// f32x8 -> bf16x8 via v_cvt_pk_bf16_f32 (compiler-lowered), as MFMA short8 frag
__device__ __forceinline__ short8_t cvt8(floatx8 f) {
  return __builtin_bit_cast(short8_t, __builtin_convertvector(f, bf16x8_t));
}
__device__ __forceinline__ uint2 cvt4pack(float4 v) {
  floatx4 f = {v.x, v.y, v.z, v.w};
  return __builtin_bit_cast(uint2, __builtin_convertvector(f, bf16x4_t));
}
__device__ __forceinline__ uint2 pack4(f32x4_t v) {
  floatx4 f = {v[0], v[1], v[2], v[3]};
  return __builtin_bit_cast(uint2, __builtin_convertvector(f, bf16x4_t));
}
__device__ __forceinline__ unsigned short bf1(float f) {
  return __builtin_bit_cast(unsigned short, (__bf16)f);
}

// Partial layout: uint2 part[s][N/16][2(half)][64(lane)]
//   lane = lg*16+lm ; uint2 = 4 bf16 rows {half*16+lg*4+0..3} of col ct*16+lm.

// ---------------- MFMA GEMM: A_bf[25][K] * W -> packed bf16 partials
// Block: 4 waves, 64*G cols; wave owns 16*G cols (G groups of 16).
// A staged in LDS as bf16. D-step-ahead register prefetch on the W stream
// ((D+1)-buffer rotation; k-loop fully unrolled -> all indices compile-time).
// WT=0: W[K][N].  WT=1: W[N][K].
template <int KC, int WT, int G, int D>
__global__ __launch_bounds__(256) void k_mfma(
    const unsigned short* __restrict__ A, const float* __restrict__ W,
    uint2* __restrict__ part, int K, int N) {
  constexpr int LDA = KC + 8;  // bf16 elems/row; +16B pad
  constexpr int NS = KC / 32;
  __shared__ __align__(16) unsigned short As[TOK * LDA];
  const int tid = threadIdx.x;
  const int lane = tid & 63;
  const int lm = lane & 15;   // A row / B col within 16
  const int lg = lane >> 4;   // k-group (8 elems)
  const int wv = tid >> 6;
  const int s = blockIdx.y;
  const int k0 = s * KC;
  const int c0 = blockIdx.x * (64 * G) + wv * (16 * G);  // wave's first col
  // ---- stage A tile: 25 x KC bf16
  for (int i = tid; i < TOK * (KC / 8); i += 256) {
    int r = i / (KC / 8);
    int o = i - r * (KC / 8);
    uint4 v = *reinterpret_cast<const uint4*>(A + (long)r * K + k0 + o * 8);
    *reinterpret_cast<uint4*>(&As[r * LDA + o * 8]) = v;
  }
  __syncthreads();
  const int r1 = 16 + lm;
  const int r1c = (r1 < TOK) ? r1 : 0;  // clamped; rows >=25 dropped in reduce
  f32x4_t acc[G][2];
#pragma unroll
  for (int g = 0; g < G; ++g) {
    acc[g][0] = (f32x4_t){0.f, 0.f, 0.f, 0.f};
    acc[g][1] = (f32x4_t){0.f, 0.f, 0.f, 0.f};
  }
  auto loadW = [&](int ks, floatx8(&dst)[G]) {
    const int kb = k0 + ks + lg * 8;
    if (WT == 0) {
      const float* bp = W + (long)kb * N + c0 + lm;
#pragma unroll
      for (int j = 0; j < 8; ++j) {
        const float* bj = bp + (long)j * N;
#pragma unroll
        for (int g = 0; g < G; ++g) dst[g][j] = bj[g * 16];
      }
    } else {
#pragma unroll
      for (int g = 0; g < G; ++g) {
        const float* bp = W + (long)(c0 + g * 16 + lm) * K + kb;
        float4 b0 = *reinterpret_cast<const float4*>(bp);
        float4 b1 = *reinterpret_cast<const float4*>(bp + 4);
        dst[g] = (floatx8){b0.x, b0.y, b0.z, b0.w, b1.x, b1.y, b1.z, b1.w};
      }
    }
  };
  floatx8 wb[D + 1][G];
  loadW(0, wb[0]);
  if (D >= 2 && NS > 1) loadW(32, wb[1 % (D + 1)]);
#pragma unroll
  for (int st = 0; st < NS; ++st) {
    if (st + D < NS) loadW((st + D) * 32, wb[(st + D) % (D + 1)]);
    short8_t av0 =
        *reinterpret_cast<const short8_t*>(&As[lm * LDA + st * 32 + lg * 8]);
    short8_t av1 =
        *reinterpret_cast<const short8_t*>(&As[r1c * LDA + st * 32 + lg * 8]);
#pragma unroll
    for (int g = 0; g < G; ++g) {
      short8_t bv = cvt8(wb[st % (D + 1)][g]);
      acc[g][0] = __builtin_amdgcn_mfma_f32_16x16x32_bf16(av0, bv, acc[g][0], 0, 0, 0);
      acc[g][1] = __builtin_amdgcn_mfma_f32_16x16x32_bf16(av1, bv, acc[g][1], 0, 0, 0);
    }
  }
  // ---- packed store: 512B contiguous per (g, half)
  const long sbase = (long)s * N * 8;  // uint2 per slice = N/16*2*64 = N*8
#pragma unroll
  for (int g = 0; g < G; ++g) {
    long t = ((long)(c0 >> 4) + g) * 128;
    part[sbase + t + lane] = pack4(acc[g][0]);
    part[sbase + t + 64 + lane] = pack4(acc[g][1]);
  }
}

// ---------------- patch-embed MFMA GEMM: A gathered from x. W=pe_w[N][K].
template <int KC, int G, int D>
__global__ __launch_bounds__(256) void k_mfma_pe(
    const float* __restrict__ x, const float* __restrict__ W,
    uint2* __restrict__ part, int K, int N) {
  constexpr int LDA = KC + 8;
  constexpr int NS = KC / 32;
  __shared__ __align__(16) unsigned short As[TOK * LDA];
  const int tid = threadIdx.x;
  const int lane = tid & 63;
  const int lm = lane & 15;
  const int lg = lane >> 4;
  const int wv = tid >> 6;
  const int s = blockIdx.y;
  const int k0 = s * KC;
  const int c0 = blockIdx.x * (64 * G) + wv * (16 * G);
  for (int i = tid; i < TOK * (KC / 8); i += 256) {
    int r = i / (KC / 8);
    int o = i - r * (KC / 8);
    int kb = k0 + o * 8;
    int c = kb >> 4;
    int kh0 = (kb >> 2) & 3;
    int py = r / 5, px = r - py * 5;
    const float* xp = x + c * 400 + (py * 4 + kh0) * 20 + px * 4;
    float4 lo = *reinterpret_cast<const float4*>(xp);
    float4 hi = *reinterpret_cast<const float4*>(xp + 20);
    floatx8 f = {lo.x, lo.y, lo.z, lo.w, hi.x, hi.y, hi.z, hi.w};
    *reinterpret_cast<short8_t*>(&As[r * LDA + o * 8]) = cvt8(f);
  }
  __syncthreads();
  const int r1 = 16 + lm;
  const int r1c = (r1 < TOK) ? r1 : 0;
  f32x4_t acc[G][2];
#pragma unroll
  for (int g = 0; g < G; ++g) {
    acc[g][0] = (f32x4_t){0.f, 0.f, 0.f, 0.f};
    acc[g][1] = (f32x4_t){0.f, 0.f, 0.f, 0.f};
  }
  auto loadW = [&](int ks, floatx8(&dst)[G]) {
    const int kb = k0 + ks + lg * 8;
#pragma unroll
    for (int g = 0; g < G; ++g) {
      const float* bp = W + (long)(c0 + g * 16 + lm) * K + kb;
      float4 b0 = *reinterpret_cast<const float4*>(bp);
      float4 b1 = *reinterpret_cast<const float4*>(bp + 4);
      dst[g] = (floatx8){b0.x, b0.y, b0.z, b0.w, b1.x, b1.y, b1.z, b1.w};
    }
  };
  floatx8 wb[D + 1][G];
  loadW(0, wb[0]);
  if (D >= 2 && NS > 1) loadW(32, wb[1 % (D + 1)]);
#pragma unroll
  for (int st = 0; st < NS; ++st) {
    if (st + D < NS) loadW((st + D) * 32, wb[(st + D) % (D + 1)]);
    short8_t av0 =
        *reinterpret_cast<const short8_t*>(&As[lm * LDA + st * 32 + lg * 8]);
    short8_t av1 =
        *reinterpret_cast<const short8_t*>(&As[r1c * LDA + st * 32 + lg * 8]);
#pragma unroll
    for (int g = 0; g < G; ++g) {
      short8_t bv = cvt8(wb[st % (D + 1)][g]);
      acc[g][0] = __builtin_amdgcn_mfma_f32_16x16x32_bf16(av0, bv, acc[g][0], 0, 0, 0);
      acc[g][1] = __builtin_amdgcn_mfma_f32_16x16x32_bf16(av1, bv, acc[g][1], 0, 0, 0);
    }
  }
  const long sbase = (long)s * N * 8;
#pragma unroll
  for (int g = 0; g < G; ++g) {
    long t = ((long)(c0 >> 4) + g) * 128;
    part[sbase + t + lane] = pack4(acc[g][0]);
    part[sbase + t + 64 + lane] = pack4(acc[g][1]);
  }
}

// ---------------- reduce packed partials + bias (+gelu) (+residual)
// 128 threads/block, grid = Nout*8/128.
template <int S, int GELU, int RES, int OBF>
__global__ __launch_bounds__(128) void k_reduce(const uint2* __restrict__ part,
                                                const float* __restrict__ bias,
                                                const float* __restrict__ res,
                                                void* __restrict__ outv,
                                                int Nout) {
  const long gidx = (long)blockIdx.x * 128 + threadIdx.x;
  const int lane = (int)(gidx & 63);
  const int half = (int)((gidx >> 6) & 1);
  const long ct = gidx >> 7;
  const int lm = lane & 15, lg = lane >> 4;
  const int col = (int)(ct * 16 + lm);
  const long stride = (long)Nout * 8;  // uint2 per s-slice
  const uint2* pp = part + gidx;
  float a[4] = {0.f, 0.f, 0.f, 0.f};
#pragma unroll 16
  for (int s = 0; s < S; ++s) {
    uint2 u = pp[(long)s * stride];
    a[0] += __builtin_bit_cast(float, (u.x & 0xffffu) << 16);
    a[1] += __builtin_bit_cast(float, u.x & 0xffff0000u);
    a[2] += __builtin_bit_cast(float, (u.y & 0xffffu) << 16);
    a[3] += __builtin_bit_cast(float, u.y & 0xffff0000u);
  }
  const float bb = bias[col];
#pragma unroll
  for (int r = 0; r < 4; ++r) {
    a[r] += bb;
    if (GELU) a[r] = 0.5f * a[r] * (1.f + erff(a[r] * 0.70710678118654752f));
  }
  const int row0 = half * 16 + lg * 4;
#pragma unroll
  for (int r = 0; r < 4; ++r) {
    int row = row0 + r;
    if (row < TOK) {
      float v = a[r];
      if (RES) v += res[(long)row * Nout + col];
      if (OBF) {
        ((unsigned short*)outv)[(long)row * Nout + col] = bf1(v);
      } else {
        ((float*)outv)[(long)row * Nout + col] = v;
      }
    }
  }
}

// ---------------- LayerNorm over 4096, one block per token -> bf16 out
__global__ __launch_bounds__(256) void k_ln(const float* __restrict__ t,
                                            const float* __restrict__ g,
                                            const float* __restrict__ b,
                                            unsigned short* __restrict__ h) {
  const int n = blockIdx.x;
  const float4* row = reinterpret_cast<const float4*>(t + n * 4096);
  float s = 0.f, s2 = 0.f;
  float4 vbuf[4];
#pragma unroll
  for (int it = 0; it < 4; ++it) {
    float4 v = row[threadIdx.x + it * 256];
    vbuf[it] = v;
    s += v.x + v.y + v.z + v.w;
    s2 += v.x * v.x + v.y * v.y + v.z * v.z + v.w * v.w;
  }
#pragma unroll
  for (int off = 32; off >= 1; off >>= 1) {
    s += __shfl_down(s, off);
    s2 += __shfl_down(s2, off);
  }
  __shared__ float red[8];
  if ((threadIdx.x & 63) == 0) {
    red[threadIdx.x >> 6] = s;
    red[4 + (threadIdx.x >> 6)] = s2;
  }
  __syncthreads();
  float st = red[0] + red[1] + red[2] + red[3];
  float s2t = red[4] + red[5] + red[6] + red[7];
  float mean = st * (1.f / 4096.f);
  float var = s2t * (1.f / 4096.f) - mean * mean;
  float rstd = rsqrtf(var + 1e-5f);
  const float4* g4 = reinterpret_cast<const float4*>(g);
  const float4* b4 = reinterpret_cast<const float4*>(b);
  uint2* h2 = reinterpret_cast<uint2*>(h) + (long)n * 1024;
#pragma unroll
  for (int it = 0; it < 4; ++it) {
    int i = threadIdx.x + it * 256;
    float4 v = vbuf[it];
    float4 gg = g4[i];
    float4 bb = b4[i];
    float4 o;
    o.x = (v.x - mean) * rstd * gg.x + bb.x;
    o.y = (v.y - mean) * rstd * gg.y + bb.y;
    o.z = (v.z - mean) * rstd * gg.z + bb.z;
    o.w = (v.w - mean) * rstd * gg.w + bb.w;
    h2[i] = cvt4pack(o);
  }
}

// ---------------- fused attention: QK^T + softmax/64 + PV -> O_bf[25][4096]
__global__ __launch_bounds__(256) void k_attn(const float* __restrict__ qkv,
                                              unsigned short* __restrict__ o) {
  const int head = blockIdx.x;
  __shared__ float q[TOK][260];
  __shared__ float kk[TOK][260];
  __shared__ float att[TOK][TOK];
  const int d = threadIdx.x;
#pragma unroll
  for (int n = 0; n < TOK; ++n) {
    const long base = (long)n * 12288 + (head * 256 + d) * 3;
    q[n][d] = qkv[base];
    kk[n][d] = qkv[base + 1];
  }
  __syncthreads();
  for (int p = threadIdx.x; p < TOK * TOK; p += 256) {
    int i = p / TOK, j = p - i * TOK;
    float acc = 0.f;
#pragma unroll
    for (int c = 0; c < 256; c += 4) {
      float4 a = *reinterpret_cast<const float4*>(&q[i][c]);
      float4 bb = *reinterpret_cast<const float4*>(&kk[j][c]);
      acc = fmaf(a.x, bb.x, acc);
      acc = fmaf(a.y, bb.y, acc);
      acc = fmaf(a.z, bb.z, acc);
      acc = fmaf(a.w, bb.w, acc);
    }
    att[i][j] = acc;
  }
  __syncthreads();
  if (threadIdx.x < TOK) {
    const int i = threadIdx.x;
    float m = -1e30f;
    for (int j = 0; j < TOK; ++j) m = fmaxf(m, att[i][j]);
    float ssum = 0.f;
    float ex[TOK];
#pragma unroll
    for (int j = 0; j < TOK; ++j) {
      ex[j] = expf(att[i][j] - m);
      ssum += ex[j];
    }
    float inv = 1.f / (ssum * 64.f);  // softmax then /sqrt(4096)
#pragma unroll
    for (int j = 0; j < TOK; ++j) att[i][j] = ex[j] * inv;
  }
  __syncthreads();
  float acc[TOK];
#pragma unroll
  for (int i = 0; i < TOK; ++i) acc[i] = 0.f;
#pragma unroll
  for (int j = 0; j < TOK; ++j) {
    float vv = qkv[(long)j * 12288 + (head * 256 + d) * 3 + 2];
#pragma unroll
    for (int i = 0; i < TOK; ++i) acc[i] = fmaf(att[i][j], vv, acc[i]);
  }
#pragma unroll
  for (int i = 0; i < TOK; ++i)
    o[(long)i * 4096 + head * 256 + d] = bf1(acc[i]);
}

extern "C" void kernel_launch(void* const* d_in, const int* in_sizes, int n_in,
                              void* d_out, int out_size, void* d_ws, size_t ws_size,
                              hipStream_t stream) {
  (void)in_sizes; (void)n_in; (void)out_size; (void)ws_size;
  const float* x      = (const float*)d_in[0];
  const float* pe_w   = (const float*)d_in[1];
  const float* pe_b   = (const float*)d_in[2];
  const float* pos    = (const float*)d_in[3];
  const float* ln_g   = (const float*)d_in[4];
  const float* ln_b   = (const float*)d_in[5];
  const float* qkv_w  = (const float*)d_in[6];
  const float* qkv_b  = (const float*)d_in[7];
  const float* proj_w = (const float*)d_in[8];
  const float* proj_b = (const float*)d_in[9];
  const float* ff1_w  = (const float*)d_in[10];
  const float* ff1_b  = (const float*)d_in[11];
  const float* ff2_w  = (const float*)d_in[12];
  const float* ff2_b  = (const float*)d_in[13];
  float* out = (float*)d_out;

  float* ws = (float*)d_ws;
  float* T    = ws + 102400;    // 102400 f32
  unsigned short* H_bf = (unsigned short*)(ws + 204800);      // 102400 bf16
  float* QKV  = ws + 307200;    // 307200 f32
  unsigned short* O_bf = (unsigned short*)(ws + 614400);      // 102400 bf16
  unsigned short* G_bf = (unsigned short*)(ws + 716800);      // 409600 bf16
  uint2* PART = (uint2*)(ws + 1136400);  // max 12.6 MB (qkv)

  // 1. patch embedding: KC=128 S=32, G=2 D=2, grid(32,32)=1024
  k_mfma_pe<128, 2, 2><<<dim3(32, 32), 256, 0, stream>>>(x, pe_w, PART, 4096, 4096);
  k_reduce<32, 0, 1, 0><<<256, 128, 0, stream>>>(PART, pe_b, pos, T, 4096);
  k_ln<<<25, 256, 0, stream>>>(T, ln_g, ln_b, H_bf);

  // 2. attention: qkv KC=256 S=16, G=2 D=2, grid(96,16)=1536
  k_mfma<256, 0, 2, 2><<<dim3(96, 16), 256, 0, stream>>>(H_bf, qkv_w, PART, 4096, 12288);
  k_reduce<16, 0, 0, 0><<<768, 128, 0, stream>>>(PART, qkv_b, nullptr, QKV, 12288);
  k_attn<<<16, 256, 0, stream>>>(QKV, O_bf);
  // proj KC=128 S=32, G=2 D=2, grid(32,32)=1024
  k_mfma<128, 0, 2, 2><<<dim3(32, 32), 256, 0, stream>>>(O_bf, proj_w, PART, 4096, 4096);
  k_reduce<32, 0, 1, 0><<<256, 128, 0, stream>>>(PART, proj_b, T, T, 4096);
  k_ln<<<25, 256, 0, stream>>>(T, ln_g, ln_b, H_bf);

  // 3. FFN: ff1 KC=256 S=16, G=4 D=1, grid(64,16)=1024; bf16 out
  k_mfma<256, 0, 4, 1><<<dim3(64, 16), 256, 0, stream>>>(H_bf, ff1_w, PART, 4096, 16384);
  k_reduce<16, 1, 0, 1><<<1024, 128, 0, stream>>>(PART, ff1_b, nullptr, G_bf, 16384);
  // ff2 KC=512 S=32, G=2 D=2, grid(32,32)=1024
  k_mfma<512, 0, 2, 2><<<dim3(32, 32), 256, 0, stream>>>(G_bf, ff2_w, PART, 16384, 4096);
  k_reduce<32, 0, 1, 0><<<256, 128, 0, stream>>>(PART, ff2_b, T, out, 4096);
}